// Round 8
// baseline (166.743 us; speedup 1.0000x reference)
//
#include <hip/hip_runtime.h>
#include <hip/hip_bf16.h>
#include <math.h>

#define BB   2
#define SS   1024
#define HIDD 768
#define NHH  12
#define HDD  64

typedef float f32x4 __attribute__((ext_vector_type(4)));
typedef short bf8   __attribute__((ext_vector_type(8)));   // 8 bf16 (bit pattern)
typedef unsigned short u16;
typedef unsigned int u32;
typedef u16 u16x8 __attribute__((ext_vector_type(8)));
typedef u16 u16x4 __attribute__((ext_vector_type(4)));

__device__ __forceinline__ u16 f2bf(float x) {  // RNE f32->bf16
  unsigned int u = __float_as_uint(x);
  u += 0x7fffu + ((u >> 16) & 1u);
  return (u16)(u >> 16);
}
__device__ __forceinline__ float bf2f(u16 x) {
  return __uint_as_float(((u32)x) << 16);
}

// Swizzled fragment read from a [R][64] bf16 LDS tile (XOR swizzle, 8-elem
// granularity). row = M/N index; kc = starting k element (multiple of 8).
__device__ __forceinline__ bf8 ldfrag(const u16* t, int row, int kc) {
  return *(const bf8*)&t[row * 64 + (kc ^ ((row & 7) << 3))];
}

// ---------------------------------------------------------------------------
// Prep: X f32 -> bf16.
// ---------------------------------------------------------------------------
__global__ __launch_bounds__(256) void xconv_kernel(const float* __restrict__ X,
                                                    u16* __restrict__ Xb) {
  int i = (blockIdx.x * 256 + threadIdx.x) * 8;
  float4 a = *(const float4*)&X[i];
  float4 b = *(const float4*)&X[i + 4];
  u16x8 o;
  o[0] = f2bf(a.x); o[1] = f2bf(a.y); o[2] = f2bf(a.z); o[3] = f2bf(a.w);
  o[4] = f2bf(b.x); o[5] = f2bf(b.y); o[6] = f2bf(b.z); o[7] = f2bf(b.w);
  *(u16x8*)&Xb[i] = o;
}

// ---------------------------------------------------------------------------
// Prep: W [k][n] f32 (x3) -> Wt [3*768 rows n][768 cols k] bf16 (transposed).
// ---------------------------------------------------------------------------
__global__ __launch_bounds__(256) void wtconv_kernel(
    const float* __restrict__ Wq, const float* __restrict__ Wk,
    const float* __restrict__ Wv, u16* __restrict__ Wt) {
  const int zi = blockIdx.z;
  const float* __restrict__ W = (zi == 0) ? Wq : (zi == 1 ? Wk : Wv);
  const int n0 = blockIdx.x * 64;
  const int k0 = blockIdx.y * 64;
  __shared__ float t[64][65];
  const int tid = threadIdx.x;
  {
    const int kl = tid >> 4;
    const int nl = (tid & 15) * 4;
#pragma unroll
    for (int p = 0; p < 4; ++p) {
      float4 v = *(const float4*)&W[(size_t)(k0 + kl + 16 * p) * HIDD + n0 + nl];
      t[kl + 16 * p][nl + 0] = v.x;
      t[kl + 16 * p][nl + 1] = v.y;
      t[kl + 16 * p][nl + 2] = v.z;
      t[kl + 16 * p][nl + 3] = v.w;
    }
  }
  __syncthreads();
  {
    const int nl = tid >> 4;
    const int cl = (tid & 15) * 4;
#pragma unroll
    for (int p = 0; p < 4; ++p) {
      const int n = nl + 16 * p;
      u16x4 o;
      o[0] = f2bf(t[cl + 0][n]);
      o[1] = f2bf(t[cl + 1][n]);
      o[2] = f2bf(t[cl + 2][n]);
      o[3] = f2bf(t[cl + 3][n]);
      *(u16x4*)&Wt[(size_t)(zi * HIDD + n0 + n) * HIDD + k0 + cl] = o;
    }
  }
}

// ---------------------------------------------------------------------------
// Prep: dist_emb f32 -> bf16.
// ---------------------------------------------------------------------------
__global__ __launch_bounds__(256) void econv_kernel(const float* __restrict__ demb,
                                                    u16* __restrict__ eb) {
  int i = (blockIdx.x * 256 + threadIdx.x) * 8;
  if (i < 2047 * HDD) {
    float4 a = *(const float4*)&demb[i];
    float4 b = *(const float4*)&demb[i + 4];
    u16x8 o;
    o[0] = f2bf(a.x); o[1] = f2bf(a.y); o[2] = f2bf(a.z); o[3] = f2bf(a.w);
    o[4] = f2bf(b.x); o[5] = f2bf(b.y); o[6] = f2bf(b.z); o[7] = f2bf(b.w);
    *(u16x8*)&eb[i] = o;
  }
}

// ---------------------------------------------------------------------------
// Prep: scaled_attention_mask f32 [S][S] -> bf16.
// ---------------------------------------------------------------------------
__global__ __launch_bounds__(256) void sconv_kernel(const float* __restrict__ sm,
                                                    u16* __restrict__ smb) {
  int i = (blockIdx.x * 256 + threadIdx.x) * 8;
  float4 a = *(const float4*)&sm[i];
  float4 b = *(const float4*)&sm[i + 4];
  u16x8 o;
  o[0] = f2bf(a.x); o[1] = f2bf(a.y); o[2] = f2bf(a.z); o[3] = f2bf(a.w);
  o[4] = f2bf(b.x); o[5] = f2bf(b.y); o[6] = f2bf(b.z); o[7] = f2bf(b.w);
  *(u16x8*)&smb[i] = o;
}

// ---------------------------------------------------------------------------
// Fused QKV MFMA GEMM (unchanged).
// ---------------------------------------------------------------------------
__global__ __launch_bounds__(256) void qkv_mfma_kernel(
    const u16* __restrict__ Xb,   // [2048][768]
    const u16* __restrict__ Wt,   // [2304][768]
    const float* __restrict__ bq, const float* __restrict__ bk,
    const float* __restrict__ bv,
    u16* __restrict__ qb, u16* __restrict__ kb, u16* __restrict__ vt) {
  const int bn = blockIdx.x;   // 0..17  (128 N-cols each)
  const int bm = blockIdx.y;   // 0..31  (64 M-rows each)
  const int zi = bn / 6;

  __shared__ u16 As[64 * 64];
  __shared__ u16 Bs[128 * 64];

  const int tid  = threadIdx.x;
  const int lane = tid & 63;
  const int w    = tid >> 6;
  const int g    = lane >> 4;
  const int ln   = lane & 15;
  const int wm   = (w >> 1) * 32;
  const int wn   = (w & 1) * 64;

  f32x4 acc[2][4] = {};

  const int srow = tid >> 3;        // 0..31
  const int scol = (tid & 7) * 8;   // 0..56
  const u16* Ag = Xb + (size_t)(bm * 64 + srow) * HIDD + scol;
  const u16* Bg = Wt + (size_t)(bn * 128 + srow) * HIDD + scol;

  for (int k0 = 0; k0 < HIDD; k0 += 64) {
    if (k0) __syncthreads();
#pragma unroll
    for (int p = 0; p < 2; ++p) {
      const int r = srow + 32 * p;
      const int sw = (r & 7) << 3;
      *(u16x8*)&As[r * 64 + (scol ^ sw)] =
          *(const u16x8*)&Ag[(size_t)(32 * p) * HIDD + k0];
    }
#pragma unroll
    for (int p = 0; p < 4; ++p) {
      const int r = srow + 32 * p;
      const int sw = (r & 7) << 3;
      *(u16x8*)&Bs[r * 64 + (scol ^ sw)] =
          *(const u16x8*)&Bg[(size_t)(32 * p) * HIDD + k0];
    }
    __syncthreads();

    bf8 af[2][2], bfr[4][2];
#pragma unroll
    for (int f = 0; f < 2; ++f)
#pragma unroll
      for (int kk = 0; kk < 2; ++kk)
        af[f][kk] = ldfrag(As, wm + 16 * f + ln, kk * 32 + g * 8);
#pragma unroll
    for (int f = 0; f < 4; ++f)
#pragma unroll
      for (int kk = 0; kk < 2; ++kk)
        bfr[f][kk] = ldfrag(Bs, wn + 16 * f + ln, kk * 32 + g * 8);
    if (zi < 2) {  // transposed output frags
#pragma unroll
      for (int mf = 0; mf < 2; ++mf)
#pragma unroll
        for (int nf = 0; nf < 4; ++nf)
#pragma unroll
          for (int kk = 0; kk < 2; ++kk)
            acc[mf][nf] = __builtin_amdgcn_mfma_f32_16x16x32_bf16(
                bfr[nf][kk], af[mf][kk], acc[mf][nf], 0, 0, 0);
    } else {
#pragma unroll
      for (int mf = 0; mf < 2; ++mf)
#pragma unroll
        for (int nf = 0; nf < 4; ++nf)
#pragma unroll
          for (int kk = 0; kk < 2; ++kk)
            acc[mf][nf] = __builtin_amdgcn_mfma_f32_16x16x32_bf16(
                af[mf][kk], bfr[nf][kk], acc[mf][nf], 0, 0, 0);
    }
  }

  const int mrow  = bm * 64 + wm;
  const int nbase = (bn % 6) * 128 + wn;  // multiple of 64 within zi
  const int h     = nbase >> 6;

  if (zi < 2) {
    const float* __restrict__ bias = zi ? bk : bq;
    u16* __restrict__ outp = zi ? kb : qb;
#pragma unroll
    for (int nf = 0; nf < 4; ++nf) {
      const int d0 = 16 * nf + 4 * g;           // d within head
      float4 bi = *(const float4*)&bias[nbase + d0];
#pragma unroll
      for (int mf = 0; mf < 2; ++mf) {
        const int m = mrow + 16 * mf + ln;      // token index
        const int b = m >> 10, s = m & 1023;
        u16x4 o;
        o[0] = f2bf(acc[mf][nf][0] + bi.x);
        o[1] = f2bf(acc[mf][nf][1] + bi.y);
        o[2] = f2bf(acc[mf][nf][2] + bi.z);
        o[3] = f2bf(acc[mf][nf][3] + bi.w);
        *(u16x4*)&outp[(((size_t)(b * NHH + h)) * SS + s) * HDD + d0] = o;
      }
    }
  } else {
#pragma unroll
    for (int nf = 0; nf < 4; ++nf) {
      const int d = 16 * nf + ln;
      const float bi = bv[nbase + d];
#pragma unroll
      for (int mf = 0; mf < 2; ++mf) {
        const int m = mrow + 16 * mf + 4 * g;   // 4 consecutive tokens
        const int b = m >> 10, s = m & 1023;
        u16x4 o;
        o[0] = f2bf(acc[mf][nf][0] + bi);
        o[1] = f2bf(acc[mf][nf][1] + bi);
        o[2] = f2bf(acc[mf][nf][2] + bi);
        o[3] = f2bf(acc[mf][nf][3] + bi);
        *(u16x4*)&vt[(((size_t)(b * NHH + h)) * HDD + d) * SS + s] = o;
      }
    }
  }
}

// ---------------------------------------------------------------------------
// Toeplitz bias precompute: Tg[bh][l][r] = q[l] . dist_emb[l-r+1023], bf16.
// Swapped T-MFMA (validated in R5-R7) + per-wave LDS gather, once per tile.
// Block: z=bh, y=l-tile(16 rows), x=r-quad; wave w -> r-tile x*4+w (64 r).
// ---------------------------------------------------------------------------
__global__ __launch_bounds__(256) void tbias_kernel(
    const u16* __restrict__ qbg,   // [B*NH][S][64] bf16
    const u16* __restrict__ eb,    // [2047][64] bf16
    u16* __restrict__ Tg) {        // [B*NH][S][S] bf16
  const int bh = blockIdx.z;
  const int l0 = blockIdx.y * 16;
  const int tid = threadIdx.x;
  const int lane = tid & 63;
  const int w = tid >> 6;
  const int g = lane >> 4;
  const int ln = lane & 15;
  const int r0 = (blockIdx.x * 4 + w) * 64;

  __shared__ u16 tb[4][80 * 20];
  u16* Tw = tb[w];

  const u16* qp = qbg + ((size_t)bh * SS + l0 + ln) * HDD + g * 8;
  const bf8 qf0 = *(const bf8*)qp;
  const bf8 qf1 = *(const bf8*)(qp + 32);

  const int W0 = l0 - r0 + 960;
#pragma unroll
  for (int c5 = 0; c5 < 5; ++c5) {
    const int gr = min(max(W0 + 16 * c5 + ln, 0), 2046);
    const u16* ep = eb + (size_t)gr * HDD + g * 8;
    f32x4 x = {0.f, 0.f, 0.f, 0.f};
    x = __builtin_amdgcn_mfma_f32_16x16x32_bf16(*(const bf8*)ep, qf0, x, 0, 0, 0);
    x = __builtin_amdgcn_mfma_f32_16x16x32_bf16(*(const bf8*)(ep + 32), qf1, x, 0, 0, 0);
#pragma unroll
    for (int i = 0; i < 4; ++i)
      Tw[(16 * c5 + 4 * g + i) * 20 + ln] = f2bf(x[i]);
  }
  // wave-local write->read: lgkmcnt ordering (no barrier needed)
#pragma unroll
  for (int ct = 0; ct < 4; ++ct) {
    const int E0 = ln + 63 - 16 * ct - 4 * g;
    u16x4 o;
    o[0] = Tw[(E0 - 0) * 20 + ln];
    o[1] = Tw[(E0 - 1) * 20 + ln];
    o[2] = Tw[(E0 - 2) * 20 + ln];
    o[3] = Tw[(E0 - 3) * 20 + ln];
    __builtin_nontemporal_store(
        o, (u16x4*)&Tg[((size_t)bh * SS + l0 + ln) * SS + r0 + 16 * ct + 4 * g]);
  }
}

// ---------------------------------------------------------------------------
// MFMA dual-branch flash attention v8: BARRIER-FREE main loop.
// 4 waves: p=w>>1 r-half [512p,512p+512), wp=w&1 q-sub-block (16 rows).
// Each wave privately stages its own KVBLK=32 K/V tile (software-pipelined:
// read frags(t) -> issue loads(t+1) -> compute -> write LDS(t+1)).
// Bias from precomputed Tg (nontemporal). Swapped QK, in-register softmax
// with defer-max (T13) + per-lane partial sums. Split-K merge at end.
// ---------------------------------------------------------------------------
__global__ __launch_bounds__(256, 3) void attn_kernel(
    const u16* __restrict__ qbg,     // [B*NH][S][64] bf16
    const u16* __restrict__ kbg,     // [B*NH][S][64] bf16
    const u16* __restrict__ vtg,     // [B*NH][64][S] bf16
    const u16* __restrict__ Tg,      // [B*NH][S][S] bf16
    const float* __restrict__ am,    // [B][S]
    const u16* __restrict__ smb,     // [S][S] bf16
    const float* __restrict__ selp,  // [B][S]
    float* __restrict__ out) {       // [B][S][768]
  // XCD-bijective swizzle: all 32 q-tiles of one (b,h) share bid&7.
  const int bid  = blockIdx.x;          // 0..767
  const int xcd  = bid & 7;
  const int idx  = bid >> 3;
  const int inner = idx & 31;
  const int grp  = idx >> 5;
  const int hg   = grp * 8 + xcd;       // 0..23
  const int h    = hg % NHH;
  const int b    = hg / NHH;
  const int l0   = inner * 32;

  const int bh = b * NHH + h;
  const size_t hoff = (size_t)bh * SS * HDD;

  __shared__ __align__(16) u16 smbuf[16384];  // 4 waves x (K 2048 | V 2048)

  const int tid  = threadIdx.x;
  const int lane = tid & 63;
  const int w    = tid >> 6;   // 0..3
  const int p    = w >> 1;     // r-half
  const int wp   = w & 1;      // q-row sub-block
  const int g    = lane >> 4;
  const int ln   = lane & 15;

  u16* ksw = smbuf + w * 4096;        // [32][64] swizzled
  u16* vsw = ksw + 2048;              // [64][32] swizzled (d-major)

  const int lq = l0 + 16 * wp + ln;   // this lane's q-row (swapped ops)
  bf8 qf[2];
  {
    const u16* qp = qbg + hoff + (size_t)lq * HDD + g * 8;
    qf[0] = *(const bf8*)qp;
    qf[1] = *(const bf8*)(qp + 32);
  }

  f32x4 acc1[4] = {}, acc2[4] = {};
  float m1 = -INFINITY, m2 = -INFINITY, sum1 = 0.f, sum2 = 0.f;

  // staging geometry (wave-private)
  const int srow = lane & 31;          // K row-local
  const int sh   = (lane >> 5) * 32;   // K col base (elems)
  const int kx   = (srow & 7) << 3;
  const int vrow = lane;               // V d-row
  const int vx   = (vrow & 3) << 3;

  const u16* kgp = kbg + hoff;
  const u16* vgp = vtg + hoff + (size_t)vrow * SS;
  const u16* Trow = Tg + ((size_t)bh * SS + lq) * SS;
  const u16* Srow = smb + (size_t)lq * SS;
  const float* Arow = am + (b << 10);

  const int S0base = 16 * ((2 * g) & 3) + ln;
  const int S1base = 16 * ((2 * g + 1) & 3) + ln;
  const bool gh = (lane & 32) != 0;    // g >= 2 -> source register pk[1]

  // prologue: load + write tile 0; prefetch aux for tile 0
  u16x8 kq[4], vq[4];
  u16x4 tbq[2], smq[2];
  f32x4 amq[2];
  {
    const int r0 = 512 * p;
    const u16* kg = kgp + (size_t)(r0 + srow) * HDD + sh;
    kq[0] = *(const u16x8*)(kg + 0);
    kq[1] = *(const u16x8*)(kg + 8);
    kq[2] = *(const u16x8*)(kg + 16);
    kq[3] = *(const u16x8*)(kg + 24);
    const u16* vg = vgp + r0;
    vq[0] = *(const u16x8*)(vg + 0);
    vq[1] = *(const u16x8*)(vg + 8);
    vq[2] = *(const u16x8*)(vg + 16);
    vq[3] = *(const u16x8*)(vg + 24);
#pragma unroll
    for (int c = 0; c < 4; ++c) {
      *(u16x8*)&ksw[srow * 64 + ((sh + 8 * c) ^ kx)] = kq[c];
      *(u16x8*)&vsw[vrow * 32 + ((8 * c) ^ vx)] = vq[c];
    }
#pragma unroll
    for (int ct = 0; ct < 2; ++ct) {
      tbq[ct] = __builtin_nontemporal_load(
          (const u16x4*)&Trow[r0 + 16 * ct + 4 * g]);
      smq[ct] = *(const u16x4*)&Srow[r0 + 16 * ct + 4 * g];
      amq[ct] = *(const f32x4*)&Arow[r0 + 16 * ct + 4 * g];
    }
  }

  for (int t = 0; t < 16; ++t) {
    const int r0 = 512 * p + 32 * t;

    // rotate prefetched aux into locals
    u16x4 tbv[2] = {tbq[0], tbq[1]};
    u16x4 smv[2] = {smq[0], smq[1]};
    f32x4 amv[2] = {amq[0], amq[1]};

    // K frags + QK (LDS tile t)
    f32x4 sc[2];
#pragma unroll
    for (int ct = 0; ct < 2; ++ct) {
      f32x4 x = {0.f, 0.f, 0.f, 0.f};
#pragma unroll
      for (int kk = 0; kk < 2; ++kk)
        x = __builtin_amdgcn_mfma_f32_16x16x32_bf16(
            ldfrag(ksw, ct * 16 + ln, kk * 32 + g * 8), qf[kk], x, 0, 0, 0);
      sc[ct] = x;
    }
    // V frags (LDS tile t)
    bf8 vbf[4];
#pragma unroll
    for (int dt = 0; dt < 4; ++dt)
      vbf[dt] = *(const bf8*)&vsw[(16 * dt + ln) * 32 + 8 * (g ^ (ln & 3))];

    // issue tile t+1 global loads (hidden under softmax below)
    if (t < 15) {
      const int rn = r0 + 32;
      const u16* kg = kgp + (size_t)(rn + srow) * HDD + sh;
      kq[0] = *(const u16x8*)(kg + 0);
      kq[1] = *(const u16x8*)(kg + 8);
      kq[2] = *(const u16x8*)(kg + 16);
      kq[3] = *(const u16x8*)(kg + 24);
      const u16* vg = vgp + rn;
      vq[0] = *(const u16x8*)(vg + 0);
      vq[1] = *(const u16x8*)(vg + 8);
      vq[2] = *(const u16x8*)(vg + 16);
      vq[3] = *(const u16x8*)(vg + 24);
#pragma unroll
      for (int ct = 0; ct < 2; ++ct) {
        tbq[ct] = __builtin_nontemporal_load(
            (const u16x4*)&Trow[rn + 16 * ct + 4 * g]);
        smq[ct] = *(const u16x4*)&Srow[rn + 16 * ct + 4 * g];
        amq[ct] = *(const f32x4*)&Arow[rn + 16 * ct + 4 * g];
      }
    }

    // scores + bias
    float s1r[2][4], s2r[2][4];
#pragma unroll
    for (int ct = 0; ct < 2; ++ct)
#pragma unroll
      for (int i = 0; i < 4; ++i) {
        const float s1 = (sc[ct][i] + bf2f(tbv[ct][i])) * 0.125f + amv[ct][i];
        s1r[ct][i] = s1;
        s2r[ct][i] = s1 * bf2f(smv[ct][i]) + amv[ct][i];
      }

    bf8 pa1, pa2;
    // ---- branch 1: defer-max softmax ----
    {
      float pmax = s1r[0][0];
#pragma unroll
      for (int ct = 0; ct < 2; ++ct)
#pragma unroll
        for (int i = 0; i < 4; ++i) pmax = fmaxf(pmax, s1r[ct][i]);
      if (!__all(pmax <= m1 + 8.f)) {
        float mx = fmaxf(pmax, __shfl_xor(pmax, 16, 64));
        mx = fmaxf(mx, __shfl_xor(mx, 32, 64));
        const float mn = fmaxf(m1, mx);
        const float scl = __expf(m1 - mn);
        m1 = mn;
        sum1 *= scl;
#pragma unroll
        for (int i = 0; i < 4; ++i) {
          const float s = __shfl(scl, (lane & 48) + 4 * g + i, 64);
#pragma unroll
          for (int dt = 0; dt < 4; ++dt) acc1[dt][i] *= s;
        }
      }
      u32 pk[2][2];
      float rs = 0.f;
#pragma unroll
      for (int ct = 0; ct < 2; ++ct) {
        const float p0 = __expf(s1r[ct][0] - m1);
        const float p1 = __expf(s1r[ct][1] - m1);
        const float p2 = __expf(s1r[ct][2] - m1);
        const float p3 = __expf(s1r[ct][3] - m1);
        rs += (p0 + p1) + (p2 + p3);
        pk[ct][0] = (u32)f2bf(p0) | ((u32)f2bf(p1) << 16);
        pk[ct][1] = (u32)f2bf(p2) | ((u32)f2bf(p3) << 16);
      }
      sum1 += rs;  // per-lane partial; reduced once at the end
      union { u32 u[4]; bf8 v; } f;
      u32 a, bb2;
      a = (u32)__shfl((int)pk[0][0], S0base, 64);
      bb2 = (u32)__shfl((int)pk[1][0], S0base, 64);
      f.u[0] = gh ? bb2 : a;
      a = (u32)__shfl((int)pk[0][1], S0base, 64);
      bb2 = (u32)__shfl((int)pk[1][1], S0base, 64);
      f.u[1] = gh ? bb2 : a;
      a = (u32)__shfl((int)pk[0][0], S1base, 64);
      bb2 = (u32)__shfl((int)pk[1][0], S1base, 64);
      f.u[2] = gh ? bb2 : a;
      a = (u32)__shfl((int)pk[0][1], S1base, 64);
      bb2 = (u32)__shfl((int)pk[1][1], S1base, 64);
      f.u[3] = gh ? bb2 : a;
      pa1 = f.v;
    }
    // ---- branch 2 ----
    {
      float pmax = s2r[0][0];
#pragma unroll
      for (int ct = 0; ct < 2; ++ct)
#pragma unroll
        for (int i = 0; i < 4; ++i) pmax = fmaxf(pmax, s2r[ct][i]);
      if (!__all(pmax <= m2 + 8.f)) {
        float mx = fmaxf(pmax, __shfl_xor(pmax, 16, 64));
        mx = fmaxf(mx, __shfl_xor(mx, 32, 64));
        const float mn = fmaxf(m2, mx);
        const float scl = __expf(m2 - mn);
        m2 = mn;
        sum2 *= scl;
#pragma unroll
        for (int i = 0; i < 4; ++i) {
          const float s = __shfl(scl, (lane & 48) + 4 * g + i, 64);
#pragma unroll
          for (int dt = 0; dt < 4; ++dt) acc2[dt][i] *= s;
        }
      }
      u32 pk[2][2];
      float rs = 0.f;
#pragma unroll
      for (int ct = 0; ct < 2; ++ct) {
        const float p0 = __expf(s2r[ct][0] - m2);
        const float p1 = __expf(s2r[ct][1] - m2);
        const float p2 = __expf(s2r[ct][2] - m2);
        const float p3 = __expf(s2r[ct][3] - m2);
        rs += (p0 + p1) + (p2 + p3);
        pk[ct][0] = (u32)f2bf(p0) | ((u32)f2bf(p1) << 16);
        pk[ct][1] = (u32)f2bf(p2) | ((u32)f2bf(p3) << 16);
      }
      sum2 += rs;
      union { u32 u[4]; bf8 v; } f;
      u32 a, bb2;
      a = (u32)__shfl((int)pk[0][0], S0base, 64);
      bb2 = (u32)__shfl((int)pk[1][0], S0base, 64);
      f.u[0] = gh ? bb2 : a;
      a = (u32)__shfl((int)pk[0][1], S0base, 64);
      bb2 = (u32)__shfl((int)pk[1][1], S0base, 64);
      f.u[1] = gh ? bb2 : a;
      a = (u32)__shfl((int)pk[0][0], S1base, 64);
      bb2 = (u32)__shfl((int)pk[1][0], S1base, 64);
      f.u[2] = gh ? bb2 : a;
      a = (u32)__shfl((int)pk[0][1], S1base, 64);
      bb2 = (u32)__shfl((int)pk[1][1], S1base, 64);
      f.u[3] = gh ? bb2 : a;
      pa2 = f.v;
    }

    // write tile t+1 into wave-private LDS (vmcnt on kq/vq; no barrier)
    if (t < 15) {
#pragma unroll
      for (int c = 0; c < 4; ++c) {
        *(u16x8*)&ksw[srow * 64 + ((sh + 8 * c) ^ kx)] = kq[c];
        *(u16x8*)&vsw[vrow * 32 + ((8 * c) ^ vx)] = vq[c];
      }
    }

    // PV (frags already in registers)
    __builtin_amdgcn_s_setprio(1);
#pragma unroll
    for (int dt = 0; dt < 4; ++dt) {
      acc1[dt] = __builtin_amdgcn_mfma_f32_16x16x32_bf16(pa1, vbf[dt], acc1[dt], 0, 0, 0);
      acc2[dt] = __builtin_amdgcn_mfma_f32_16x16x32_bf16(pa2, vbf[dt], acc2[dt], 0, 0, 0);
    }
    __builtin_amdgcn_s_setprio(0);
  }

  // reduce per-lane partial sums -> row totals (row-uniform)
  sum1 += __shfl_xor(sum1, 16, 64);
  sum1 += __shfl_xor(sum1, 32, 64);
  sum2 += __shfl_xor(sum2, 16, 64);
  sum2 += __shfl_xor(sum2, 32, 64);

  // -------- cross-pair combine (split-K merge) --------
  __syncthreads();
  float* scr = (float*)smbuf;  // 4224 floats, overlays dead K/V tiles
  if (p == 1) {
#pragma unroll
    for (int i = 0; i < 4; ++i) {
      const int row = 4 * g + i;
#pragma unroll
      for (int dt = 0; dt < 4; ++dt) {
        scr[wp * 1024 + row * 64 + dt * 16 + ln] = acc1[dt][i];
        scr[2048 + wp * 1024 + row * 64 + dt * 16 + ln] = acc2[dt][i];
      }
    }
    if (g == 0) {  // one lane per q-row publishes stats (q = ln)
      const int sb = 4096 + (wp * 16 + ln) * 4;
      scr[sb + 0] = m1;
      scr[sb + 1] = sum1;
      scr[sb + 2] = m2;
      scr[sb + 3] = sum2;
    }
  }
  __syncthreads();
  if (p == 0) {
    const int sb = 4096 + (wp * 16 + ln) * 4;
    const float mB1 = scr[sb + 0], sB1 = scr[sb + 1];
    const float mB2 = scr[sb + 2], sB2 = scr[sb + 3];
    const float M1 = fmaxf(m1, mB1);
    const float e1A = __expf(m1 - M1), e1B = __expf(mB1 - M1);
    const float inv1 = 1.f / (sum1 * e1A + sB1 * e1B);
    const float a1 = e1A * inv1, c1 = e1B * inv1;  // per-lane, q = ln
    const float M2 = fmaxf(m2, mB2);
    const float e2A = __expf(m2 - M2), e2B = __expf(mB2 - M2);
    const float inv2 = 1.f / (sum2 * e2A + sB2 * e2B);
    const float a2 = e2A * inv2, c2 = e2B * inv2;
#pragma unroll
    for (int i = 0; i < 4; ++i) {
      const int src = (lane & 48) + 4 * g + i;
      const float a1s = __shfl(a1, src, 64), c1s = __shfl(c1, src, 64);
      const float a2s = __shfl(a2, src, 64), c2s = __shfl(c2, src, 64);
      const int row = 4 * g + i;
      const int lg = l0 + 16 * wp + row;
      const float se = selp[(b << 10) + lg];
#pragma unroll
      for (int dt = 0; dt < 4; ++dt) {
        const float aB1 = scr[wp * 1024 + row * 64 + dt * 16 + ln];
        const float aB2 = scr[2048 + wp * 1024 + row * 64 + dt * 16 + ln];
        const float o1 = acc1[dt][i] * a1s + aB1 * c1s;
        const float o2 = acc2[dt][i] * a2s + aB2 * c2s;
        out[((size_t)((b << 10) + lg)) * HIDD + h * HDD + dt * 16 + ln] =
            se * o2 + (1.f - se) * o1;
      }
    }
  }
}

extern "C" void kernel_launch(void* const* d_in, const int* in_sizes, int n_in,
                              void* d_out, int out_size, void* d_ws, size_t ws_size,
                              hipStream_t stream) {
  const float* hidden = (const float*)d_in[0];
  const float* am     = (const float*)d_in[1];
  const float* smask  = (const float*)d_in[2];
  const float* selp   = (const float*)d_in[3];
  const float* Wq     = (const float*)d_in[4];
  const float* bq     = (const float*)d_in[5];
  const float* Wk     = (const float*)d_in[6];
  const float* bk     = (const float*)d_in[7];
  const float* Wv     = (const float*)d_in[8];
  const float* bv     = (const float*)d_in[9];
  const float* demb   = (const float*)d_in[10];
  float* out = (float*)d_out;

  u16* wsp = (u16*)d_ws;
  const size_t NEL = (size_t)BB * NHH * SS * HDD;  // 1572864
  u16* Xb  = wsp;                          // 2048*768
  u16* Wt  = Xb + (size_t)2048 * HIDD;     // 2304*768
  u16* qbw = Wt + (size_t)3 * HIDD * HIDD;
  u16* kbw = qbw + NEL;
  u16* vtw = kbw + NEL;
  u16* ebw = vtw + NEL;                    // 2047*64
  u16* smb = ebw + (size_t)2047 * HDD;     // 1024*1024
  u16* Tgw = smb + (size_t)SS * SS;        // 24*1024*1024 bf16 (48MB)

  xconv_kernel<<<768, 256, 0, stream>>>(hidden, Xb);
  dim3 gw(HIDD / 64, HIDD / 64, 3);
  wtconv_kernel<<<gw, 256, 0, stream>>>(Wq, Wk, Wv, Wt);
  econv_kernel<<<64, 256, 0, stream>>>(demb, ebw);
  sconv_kernel<<<512, 256, 0, stream>>>(smask, smb);

  dim3 g1(18, 32);
  qkv_mfma_kernel<<<g1, 256, 0, stream>>>(Xb, Wt, bq, bk, bv, qbw, kbw, vtw);

  dim3 gt(4, 64, BB * NHH);
  tbias_kernel<<<gt, 256, 0, stream>>>(qbw, ebw, Tgw);

  attn_kernel<<<768, 256, 0, stream>>>(qbw, kbw, vtw, Tgw, am, smb, selp, out);
}